// Round 2
// baseline (130.597 us; speedup 1.0000x reference)
//
#include <hip/hip_runtime.h>

#define BB 8
#define SS 4096
#define EE 256
#define CHUNKS 128
#define ROWS (SS / CHUNKS)   // 32 rows per block, 8 per wave

// Workspace layout (floats):
//   sx : [0,    2048)   sum of valid x rows per batch      [B][E]
//   u  : [2048, 4096)   Wk^T @ sq                          [B][E]
//   c  : [4096, 4104)   sq . bk                            [B]
//   y  : [4104, 6152)   sum w_s * x_s                      [B][E]
//   W  : [6152, 6160)   sum w_s                            [B]
#define WS_SX 0
#define WS_U  2048
#define WS_C  4096
#define WS_Y  4104
#define WS_W  6152
#define WS_FLOATS 8192

// Pass 1: sx[b][e] = sum_{s<len} x[b,s,e]
__global__ __launch_bounds__(256) void k1_sumx(
    const float* __restrict__ x, const int* __restrict__ lengths,
    float* __restrict__ sx)
{
    const int b = blockIdx.y, chunk = blockIdx.x;
    const int len = lengths[b];
    const int tid = threadIdx.x, wid = tid >> 6, lane = tid & 63;
    const int base = chunk * ROWS;
    if (base >= len) return;                  // block-uniform
    const float4* xb = (const float4*)(x + (size_t)b * SS * EE);
    float4 acc = make_float4(0.f, 0.f, 0.f, 0.f);
    for (int r = wid; r < ROWS; r += 4) {
        const int row = base + r;             // wave-uniform predicate
        if (row < len) {
            float4 xv = xb[(size_t)row * (EE / 4) + lane];
            acc.x += xv.x; acc.y += xv.y; acc.z += xv.z; acc.w += xv.w;
        }
    }
    __shared__ float ysh[4][EE];
    ((float4*)ysh[wid])[lane] = acc;
    __syncthreads();
    float v = ysh[0][tid] + ysh[1][tid] + ysh[2][tid] + ysh[3][tid];
    atomicAdd(&sx[b * EE + tid], v);
}

// Tiny per-batch: sq = Wq sx + len*bq ; u = Wk^T sq ; c = sq . bk
__global__ __launch_bounds__(256) void k2_small(
    const float* __restrict__ Wq, const float* __restrict__ bq,
    const float* __restrict__ Wk, const float* __restrict__ bk,
    const int* __restrict__ lengths, const float* __restrict__ sx,
    float* __restrict__ u, float* __restrict__ c)
{
    const int b = blockIdx.x, t = threadIdx.x;
    __shared__ float sxs[EE];
    __shared__ float sqs[EE];
    sxs[t] = sx[b * EE + t];
    __syncthreads();
    const float lenf = (float)lengths[b];
    float acc = 0.f;
    const float* wrow = Wq + t * EE;
    #pragma unroll 8
    for (int e = 0; e < EE; ++e) acc += wrow[e] * sxs[e];
    sqs[t] = acc + lenf * bq[t];
    __syncthreads();
    float ua = 0.f;
    #pragma unroll 8
    for (int f = 0; f < EE; ++f) ua += Wk[f * EE + t] * sqs[f];  // coalesced
    u[b * EE + t] = ua;
    float p = sqs[t] * bk[t];
    #pragma unroll
    for (int m = 32; m; m >>= 1) p += __shfl_xor(p, m, 64);
    __shared__ float cred[4];
    if ((t & 63) == 0) cred[t >> 6] = p;
    __syncthreads();
    if (t == 0) c[b] = cred[0] + cred[1] + cred[2] + cred[3];
}

// Pass 2: w_s = u.x_s + c ; y += w_s x_s ; W += w_s   (valid rows only)
__global__ __launch_bounds__(256) void k3_main(
    const float* __restrict__ x, const int* __restrict__ lengths,
    const float* __restrict__ u, const float* __restrict__ c,
    float* __restrict__ y, float* __restrict__ Wp)
{
    const int b = blockIdx.y, chunk = blockIdx.x;
    const int len = lengths[b];
    const int tid = threadIdx.x, wid = tid >> 6, lane = tid & 63;
    const int base = chunk * ROWS;
    if (base >= len) return;                  // block-uniform
    const float4 uv = ((const float4*)(u + b * EE))[lane];
    const float cb = c[b];
    const float4* xb = (const float4*)(x + (size_t)b * SS * EE);
    float4 yacc = make_float4(0.f, 0.f, 0.f, 0.f);
    float Wacc = 0.f;
    for (int r = wid; r < ROWS; r += 4) {
        const int row = base + r;             // wave-uniform predicate
        if (row < len) {
            float4 xv = xb[(size_t)row * (EE / 4) + lane];
            float p = uv.x * xv.x + uv.y * xv.y + uv.z * xv.z + uv.w * xv.w;
            #pragma unroll
            for (int m = 1; m < 64; m <<= 1) p += __shfl_xor(p, m, 64);
            p += cb;                          // w_s, broadcast to all lanes
            yacc.x += p * xv.x; yacc.y += p * xv.y;
            yacc.z += p * xv.z; yacc.w += p * xv.w;
            Wacc += p;
        }
    }
    __shared__ float ysh[4][EE];
    __shared__ float wsh[4];
    ((float4*)ysh[wid])[lane] = yacc;
    if (lane == 0) wsh[wid] = Wacc;
    __syncthreads();
    float v = ysh[0][tid] + ysh[1][tid] + ysh[2][tid] + ysh[3][tid];
    atomicAdd(&y[b * EE + tid], v);
    if (tid == 0) atomicAdd(&Wp[b], wsh[0] + wsh[1] + wsh[2] + wsh[3]);
}

// Epilogue: out[b][f] = (Wv[f,:] . y[b] + W[b]*bv[f]) / S
__global__ __launch_bounds__(256) void k4_out(
    const float* __restrict__ Wv, const float* __restrict__ bv,
    const float* __restrict__ y, const float* __restrict__ Wp,
    float* __restrict__ out)
{
    const int b = blockIdx.x, t = threadIdx.x;
    __shared__ float ysh[EE];
    ysh[t] = y[b * EE + t];
    __syncthreads();
    const float Wb = Wp[b];
    float acc = 0.f;
    const float* wrow = Wv + t * EE;
    #pragma unroll 8
    for (int e = 0; e < EE; ++e) acc += wrow[e] * ysh[e];
    out[b * EE + t] = (acc + Wb * bv[t]) * (1.0f / SS);
}

extern "C" void kernel_launch(void* const* d_in, const int* in_sizes, int n_in,
                              void* d_out, int out_size, void* d_ws, size_t ws_size,
                              hipStream_t stream) {
    const float* x  = (const float*)d_in[0];
    const float* Wq = (const float*)d_in[1];
    const float* bq = (const float*)d_in[2];
    const float* Wk = (const float*)d_in[3];
    const float* bk = (const float*)d_in[4];
    const float* Wv = (const float*)d_in[5];
    const float* bv = (const float*)d_in[6];
    const int* lengths = (const int*)d_in[7];
    float* out = (float*)d_out;
    float* ws = (float*)d_ws;

    float* sx = ws + WS_SX;
    float* u  = ws + WS_U;
    float* c  = ws + WS_C;
    float* y  = ws + WS_Y;
    float* Wp = ws + WS_W;

    hipMemsetAsync(d_ws, 0, WS_FLOATS * sizeof(float), stream);

    dim3 grid1(CHUNKS, BB);
    k1_sumx<<<grid1, 256, 0, stream>>>(x, lengths, sx);
    k2_small<<<BB, 256, 0, stream>>>(Wq, bq, Wk, bk, lengths, sx, u, c);
    k3_main<<<grid1, 256, 0, stream>>>(x, lengths, u, c, y, Wp);
    k4_out<<<BB, 256, 0, stream>>>(Wv, bv, y, Wp, out);
}